// Round 11
// baseline (163.645 us; speedup 1.0000x reference)
//
#include <hip/hip_runtime.h>
#include <hip/hip_bf16.h>
#include <hip/hip_cooperative_groups.h>

namespace cg = cooperative_groups;

#define LD 2048
#define DD 256

typedef unsigned short ushort_t;
typedef __attribute__((ext_vector_type(8))) short short8;
typedef __attribute__((ext_vector_type(4))) float floatx4;

__device__ __forceinline__ ushort_t f2bfu(float x) {
  __hip_bfloat16 h = __float2bfloat16(x);
  return *reinterpret_cast<ushort_t*>(&h);
}

// async global->LDS DMA, 16 B per lane; LDS dest = wave-uniform base + lane*16
__device__ __forceinline__ void dma16(const ushort_t* g, ushort_t* l) {
  __builtin_amdgcn_global_load_lds(
      (const __attribute__((address_space(1))) unsigned int*)g,
      (__attribute__((address_space(3))) unsigned int*)l,
      16, 0, 0);
}

// s_waitcnt imm: vmcnt lo[3:0] hi[15:14], expcnt[6:4]=7, lgkmcnt[11:8]=0xF (unmasked)
#define WAIT_VM10 0x0F7A   // vmcnt(10)
#define WAIT_VM18 0x4F72   // vmcnt(18)

// accurate sin/cos for args up to ~200 rad: one Cody-Waite step, then hw trig
__device__ __forceinline__ float sin_acc(float a) {
  float k = rintf(a * 0.15915494f);
  float r = __builtin_fmaf(-k, 6.2831855f, a);
  r = __builtin_fmaf(-k, -1.7484555e-7f, r);
  return __sinf(r);
}
__device__ __forceinline__ float cos_acc(float a) {
  float k = rintf(a * 0.15915494f);
  float r = __builtin_fmaf(-k, 6.2831855f, a);
  r = __builtin_fmaf(-k, -1.7484555e-7f, r);
  return __cosf(r);
}

// analytic A-fragment: 8 softmax-numerator weights for row i vs j in [j0, j0+8)
__device__ __forceinline__ short8 make_af(float ti, int i, int j0, const float* tj,
                                          float il, float ll, float is2) {
  short8 af;
  #pragma unroll
  for (int v = 0; v < 8; ++v) {
    float dt = ti - tj[v];
    float sk = __expf(-dt * dt * il);
    float rg = __builtin_amdgcn_rcpf(__expf((dt * 0.005f - ll) * is2) + 1.0f);
    float w = __expf(sk * (1.5f - rg));   // exp(sk*gate), gate = 1.5 - 1/(e^{2z}+1)
    w = (j0 + v <= i) ? w : 0.0f;         // causal mask
    af[v] = (short)f2bfu(w);
  }
  return af;
}

// ======================= ONE cooperative kernel, 3 phases =======================
// grid 512 x 128; __launch_bounds__(128,2) caps VGPR at 256 (>=4 blocks/CU by VGPR);
// LDS 64 KB -> 2 blocks/CU -> co-residency capacity 512 == grid.
__global__ __launch_bounds__(128, 2) void k_fused(
    const int* __restrict__ etype, const float* __restrict__ etime,
    const float* __restrict__ embw, const float* __restrict__ gatew,
    const float* __restrict__ gateb, const float* __restrict__ kerw,
    const float* __restrict__ kerb, const float* __restrict__ gamma,
    const float* __restrict__ beta, const float* __restrict__ wi,
    const float* __restrict__ wn, const float* __restrict__ wo,
    const float* __restrict__ bo, const float* __restrict__ noise,
    float* __restrict__ out, ushort_t* __restrict__ enc_bf,
    ushort_t* __restrict__ noise_bf, ushort_t* __restrict__ wcat,
    float* __restrict__ ptable, ushort_t* __restrict__ hidden_bf)
{
  __shared__ __align__(16) ushort_t stage[2][2][8192];   // 64 KB: [wave][buf][16 KB]
  const int tid = threadIdx.x;
  const int lane = tid & 63, wv = tid >> 6;
  const int bk = blockIdx.x;
  const int m = lane & 15, kg = lane >> 4;
  const int qd = lane >> 4;
  cg::grid_group gg = cg::this_grid();

  // ================= Phase A: prep (enc tile bk + cast slice bk + dots) =================
  {
    float* ts = (float*)&stage[0][0][0];
    if (tid < 32) ts[tid] = etime[(bk >> 6) * LD + (bk & 63) * 32 + tid];
    __syncthreads();
    uint4* dst = (uint4*)(enc_bf + (size_t)bk * 8192);
    #pragma unroll
    for (int it = 0; it < 8; ++it) {       // full tile: 1024 uint4 (d = 0..255)
      int u = it * 128 + tid;
      int d = u >> 2, jb = (u & 3) * 8;
      float freq = __expf(-0.07195578416f * (float)d);   // 10000^(-2d/256)
      unsigned int pk[4];
      #pragma unroll
      for (int p = 0; p < 4; ++p) {
        float a0 = ts[jb + 2 * p] * freq;
        float a1 = ts[jb + 2 * p + 1] * freq;
        float v0 = (d & 1) ? cos_acc(a0) : sin_acc(a0);
        float v1 = (d & 1) ? cos_acc(a1) : sin_acc(a1);
        pk[p] = (unsigned int)f2bfu(v0) | ((unsigned int)f2bfu(v1) << 16);
      }
      dst[u] = make_uint4(pk[0], pk[1], pk[2], pk[3]);
    }
  }
  #pragma unroll 1
  for (int it = 0; it < 17; ++it) {        // cast noise + wcat (B-frag-native)
    int idx = it * 65536 + bk * 128 + tid;
    if (idx < 1081344) {
      if (idx < 1048576) {
        float4 f = ((const float4*)noise)[idx];
        ushort4 u;
        u.x = f2bfu(f.x); u.y = f2bfu(f.y); u.z = f2bfu(f.z); u.w = f2bfu(f.w);
        *(ushort4*)(noise_bf + (size_t)idx * 4) = u;
      } else {
        int p = idx - 1048576;             // 0..32767
        int c = p >> 7;
        int k = (p & 127) * 4;
        const float* src = (k < 256) ? (wn + c * 256 + k) : (wi + c * 256 + k - 256);
        float4 f = *(const float4*)src;
        ushort4 u;
        u.x = f2bfu(f.x); u.y = f2bfu(f.y); u.z = f2bfu(f.z); u.w = f2bfu(f.w);
        *(ushort4*)(wcat + ((size_t)(c >> 4) * 16 + (k >> 5)) * 512
                         + (c & 15) * 32 + (k & 31)) = u;
      }
    }
  }
  if (bk == 511) {                         // per-type params
    __syncthreads();
    float* red = (float*)&stage[0][0][0];
    for (int ty = 0; ty < 2; ++ty) {
      float p1 = 0.f, p2 = 0.f, p3 = 0.f;
      for (int dd = tid; dd < 256; dd += 128) {
        float te = embw[ty * DD + dd] * 16.0f;   // * sqrt(256)
        p1 += te * kerw[dd];
        p2 += te * gatew[dd];
        p3 += te * gatew[DD + dd];
      }
      #pragma unroll
      for (int off = 32; off > 0; off >>= 1) {
        p1 += __shfl_xor(p1, off);
        p2 += __shfl_xor(p2, off);
        p3 += __shfl_xor(p3, off);
      }
      if (lane == 0) { red[wv * 3 + 0] = p1; red[wv * 3 + 1] = p2; red[wv * 3 + 2] = p3; }
      __syncthreads();
      if (tid == 0) {
        float s1 = red[0] + red[3] + kerb[0];
        float s2 = red[1] + red[4] + gateb[0];
        float s3 = red[2] + red[5] + gateb[1];
        float z = 0.2f * s1;
        float sp = (z > 15.0f) ? z : log1pf(__expf(z));
        float ls = 5.0f * sp;              // softplus(0.2x)/0.2
        ptable[ty * 4 + 0] = 1.0f / (ls * ls);
        ptable[ty * 4 + 1] = 1.0f / (1.0f + __expf(-s2));
        float s = 1.0f / (1.0f + __expf(-s3));
        ptable[ty * 4 + 2] = 1.0f / s;
      }
      __syncthreads();
    }
  }
  __threadfence();
  gg.sync();

  // ================= Phase B: attention, block = (b, pair), full D =================
  // Tiles tlA=pr (small) and tlB=127-pr (big) share every staged chunk. 2 waves
  // parity-split chunks; 16 KB/chunk staged once per parity wave, double-buffered,
  // >=16 DMAs outstanding via vmcnt(18); LN fully intra-block.
  const int b = bk & 7;
  const int pr = bk >> 3;                  // 0..63
  const int tlA = pr, tlB = 127 - pr;
  const int base = b * LD;
  const int iA = tlA * 16 + m, iB = tlB * 16 + m;
  const float tiA = etime[base + iA], tiB = etime[base + iB];
  const int tyA = etype[base + iA], tyB = etype[base + iB];
  const float ilA = ptable[tyA * 4 + 0], llA = ptable[tyA * 4 + 1];
  const float isA = 2.0f * ptable[tyA * 4 + 2];
  const float ilB = ptable[tyB * 4 + 0], llB = ptable[tyB * 4 + 1];
  const float isB = 2.0f * ptable[tyB * 4 + 2];
  floatx4 aA[16], aB[16];
  #pragma unroll
  for (int q = 0; q < 16; ++q) {
    aA[q] = (floatx4){0.f, 0.f, 0.f, 0.f};
    aB[q] = (floatx4){0.f, 0.f, 0.f, 0.f};
  }
  const int limA = tlA >> 1;
  const int nch = (tlB >> 1) + 1;          // 33..64
  const int myn = (nch - wv + 1) >> 1;     // >=16
  const ushort_t* __restrict__ encC = enc_bf + (size_t)(b * 64) * 8192;
  const int boff = m * 32 + kg * 8;
  ushort_t* buf0 = &stage[wv][0][0];
  ushort_t* buf1 = &stage[wv][1][0];
  short8 afA, afB;
  int ch = wv;
  {  // prologue: tj first (so make_af's wait leaves the 16 DMAs in flight)
    float4 ta = *(const float4*)(etime + base + ch * 32 + kg * 8);
    float4 tc = *(const float4*)(etime + base + ch * 32 + kg * 8 + 4);
    const ushort_t* g = encC + (size_t)ch * 8192 + lane * 8;
    #pragma unroll
    for (int q = 0; q < 16; ++q) dma16(g + q * 512, buf0 + q * 512);
    float tj[8] = {ta.x, ta.y, ta.z, ta.w, tc.x, tc.y, tc.z, tc.w};
    afB = make_af(tiB, iB, ch * 32 + kg * 8, tj, ilB, llB, isB);
    if (ch <= limA) afA = make_af(tiA, iA, ch * 32 + kg * 8, tj, ilA, llA, isA);
  }
  #pragma unroll 1
  for (int it = 0; it < myn; ++it) {
    const bool more = (it + 1 < myn);
    const int chn = more ? ch + 2 : wv;    // clamp keeps waitcnt arithmetic constant
    ushort_t* bcur = (it & 1) ? buf1 : buf0;
    ushort_t* bnxt = (it & 1) ? buf0 : buf1;
    float4 na = *(const float4*)(etime + base + chn * 32 + kg * 8);
    float4 nc = *(const float4*)(etime + base + chn * 32 + kg * 8 + 4);
    {
      const ushort_t* g = encC + (size_t)chn * 8192 + lane * 8;
      #pragma unroll
      for (int q = 0; q < 16; ++q) dma16(g + q * 512, bnxt + q * 512);
    }
    __builtin_amdgcn_s_waitcnt(WAIT_VM18); // cur 16 landed; 2 tj + 16 next in flight
    if (ch <= limA) {
      #pragma unroll
      for (int q = 0; q < 16; ++q) {
        short8 bf = *(const short8*)(bcur + q * 512 + boff);
        aB[q] = __builtin_amdgcn_mfma_f32_16x16x32_bf16(afB, bf, aB[q], 0, 0, 0);
        aA[q] = __builtin_amdgcn_mfma_f32_16x16x32_bf16(afA, bf, aA[q], 0, 0, 0);
      }
    } else {
      #pragma unroll
      for (int q = 0; q < 16; ++q) {
        short8 bf = *(const short8*)(bcur + q * 512 + boff);
        aB[q] = __builtin_amdgcn_mfma_f32_16x16x32_bf16(afB, bf, aB[q], 0, 0, 0);
      }
    }
    if (more) {
      float tj[8] = {na.x, na.y, na.z, na.w, nc.x, nc.y, nc.z, nc.w};
      afB = make_af(tiB, iB, chn * 32 + kg * 8, tj, ilB, llB, isB);
      if (chn <= limA) afA = make_af(tiA, iA, chn * 32 + kg * 8, tj, ilA, llA, isA);
    }
    ch = chn;
  }
  // ---- combine parities, LN (full D, intra-block), write bf16 hidden ----
  __syncthreads();                         // drains all outstanding DMA too
  floatx4* redx = (floatx4*)&stage[0][0][0];
  if (wv == 1) {
    #pragma unroll
    for (int q = 0; q < 16; ++q) redx[q * 64 + lane] = aA[q];
    #pragma unroll
    for (int q = 0; q < 16; ++q) redx[(16 + q) * 64 + lane] = aB[q];
  }
  __syncthreads();
  if (wv == 0) {
    #pragma unroll
    for (int q = 0; q < 16; ++q) {
      aA[q] += redx[q * 64 + lane];
      aB[q] += redx[(16 + q) * 64 + lane];
    }
    float gl[16], cl[16];
    #pragma unroll
    for (int q = 0; q < 16; ++q) { gl[q] = gamma[q * 16 + m]; cl[q] = beta[q * 16 + m]; }
    #pragma unroll
    for (int T = 0; T < 2; ++T) {
      const int tl = T ? tlB : tlA;
      #pragma unroll
      for (int r = 0; r < 4; ++r) {
        float h[16];
        float sm = 0.f, sq = 0.f;
        #pragma unroll
        for (int q = 0; q < 16; ++q) {
          h[q] = T ? aB[q][r] : aA[q][r];
          sm += h[q]; sq += h[q] * h[q];
        }
        #pragma unroll
        for (int off = 1; off < 16; off <<= 1) {
          sm += __shfl_xor(sm, off);
          sq += __shfl_xor(sq, off);
        }
        float mean = sm * (1.0f / 256.0f);
        float var = sq * (1.0f / 256.0f) - mean * mean;
        float rstd = rsqrtf(var + 1e-6f);
        ushort_t* dst = hidden_bf + (size_t)(base + tl * 16 + qd * 4 + r) * DD + m;
        #pragma unroll
        for (int q = 0; q < 16; ++q)
          dst[q * 16] = f2bfu((h[q] - mean) * rstd * gl[q] + cl[q]);
      }
    }
  }
  __threadfence();
  gg.sync();

  // ================= Phase C: generator, 2 tiles per block, waves = K-halves ======
  #pragma unroll 1
  for (int u = 0; u < 2; ++u) {
    const int t = bk * 2 + u;
    const ushort_t* __restrict__ ar =
        ((wv == 0) ? noise_bf : hidden_bf) + (size_t)(t * 16 + m) * DD;
    floatx4 g[16];
    #pragma unroll
    for (int nt = 0; nt < 16; ++nt) g[nt] = (floatx4){0.f, 0.f, 0.f, 0.f};
    #pragma unroll 1
    for (int ksl = 0; ksl < 8; ++ksl) {
      const int ksg = wv * 8 + ksl;
      short8 a = *(const short8*)(ar + ksl * 32 + kg * 8);
      #pragma unroll
      for (int nt = 0; nt < 16; ++nt) {
        short8 bfr = *(const short8*)(wcat + ((size_t)nt * 16 + ksg) * 512 + boff);
        g[nt] = __builtin_amdgcn_mfma_f32_16x16x32_bf16(a, bfr, g[nt], 0, 0, 0);
      }
    }
    __syncthreads();
    floatx4* redc = (floatx4*)&stage[0][0][0];
    if (wv == 1) {
      #pragma unroll
      for (int nt = 0; nt < 16; ++nt) redc[nt * 64 + lane] = g[nt];
    }
    __syncthreads();
    if (wv == 0) {
      #pragma unroll
      for (int nt = 0; nt < 16; ++nt) g[nt] += redc[nt * 64 + lane];
      float wo_l[16];
      #pragma unroll
      for (int nt = 0; nt < 16; ++nt) wo_l[nt] = wo[nt * 16 + m];
      const float bo_ = bo[0];
      #pragma unroll
      for (int r4 = 0; r4 < 4; ++r4) {
        float p = 0.f;
        #pragma unroll
        for (int nt = 0; nt < 16; ++nt) p += fmaxf(g[nt][r4], 0.f) * wo_l[nt];
        #pragma unroll
        for (int off = 1; off < 16; off <<= 1) p += __shfl_xor(p, off);
        if (m == 0) {
          float x = p + bo_;
          out[t * 16 + qd * 4 + r4] = (x > 15.0f) ? x : log1pf(__expf(x));
        }
      }
    }
    __syncthreads();
  }
}

// ======================= Fallback path (r9, known-good) =======================
__global__ __launch_bounds__(256) void kf_prep(
    const int* __restrict__ etype, const float* __restrict__ etime,
    const float* __restrict__ embw, const float* __restrict__ gatew,
    const float* __restrict__ gateb, const float* __restrict__ kerw,
    const float* __restrict__ kerb, const float* __restrict__ noise,
    const float* __restrict__ wn, const float* __restrict__ wi,
    ushort_t* __restrict__ enc_bf, ushort_t* __restrict__ noise_bf,
    ushort_t* __restrict__ wcat, float* __restrict__ ptable)
{
  const int bk = blockIdx.x;
  const int tid = threadIdx.x;
  if (bk < 4224) {
    int idx = bk * 256 + tid;
    if (idx < 1048576) {
      float4 f = ((const float4*)noise)[idx];
      ushort4 u;
      u.x = f2bfu(f.x); u.y = f2bfu(f.y); u.z = f2bfu(f.z); u.w = f2bfu(f.w);
      *(ushort4*)(noise_bf + (size_t)idx * 4) = u;
    } else {
      int p = idx - 1048576;
      int c = p >> 7;
      int k = (p & 127) * 4;
      const float* src = (k < 256) ? (wn + c * 256 + k) : (wi + c * 256 + k - 256);
      float4 f = *(const float4*)src;
      ushort4 u;
      u.x = f2bfu(f.x); u.y = f2bfu(f.y); u.z = f2bfu(f.z); u.w = f2bfu(f.w);
      *(ushort4*)(wcat + ((size_t)(c >> 4) * 16 + (k >> 5)) * 512
                       + (c & 15) * 32 + (k & 31)) = u;
    }
  } else if (bk < 4736) {
    int ebk = bk - 4224;
    __shared__ float ts[32];
    if (tid < 32) ts[tid] = etime[(ebk >> 6) * LD + (ebk & 63) * 32 + tid];
    __syncthreads();
    uint4* dst = (uint4*)(enc_bf + (size_t)ebk * 8192);
    const int jb = (tid & 3) * 8;
    #pragma unroll
    for (int jblk = 0; jblk < 4; ++jblk) {
      int d = jblk * 64 + (tid >> 2);
      float freq = __expf(-0.07195578416f * (float)d);
      unsigned int pk[4];
      #pragma unroll
      for (int p = 0; p < 4; ++p) {
        float a0 = ts[jb + 2 * p] * freq;
        float a1 = ts[jb + 2 * p + 1] * freq;
        float v0 = (d & 1) ? cos_acc(a0) : sin_acc(a0);
        float v1 = (d & 1) ? cos_acc(a1) : sin_acc(a1);
        pk[p] = (unsigned int)f2bfu(v0) | ((unsigned int)f2bfu(v1) << 16);
      }
      dst[jblk * 256 + tid] = make_uint4(pk[0], pk[1], pk[2], pk[3]);
    }
  } else {
    __shared__ float red[4][3];
    int lane = tid & 63, wvi = tid >> 6;
    for (int ty = 0; ty < 2; ++ty) {
      float te = embw[ty * DD + tid] * 16.0f;
      float p1 = te * kerw[tid];
      float p2 = te * gatew[tid];
      float p3 = te * gatew[DD + tid];
      #pragma unroll
      for (int off = 32; off > 0; off >>= 1) {
        p1 += __shfl_xor(p1, off);
        p2 += __shfl_xor(p2, off);
        p3 += __shfl_xor(p3, off);
      }
      if (lane == 0) { red[wvi][0] = p1; red[wvi][1] = p2; red[wvi][2] = p3; }
      __syncthreads();
      if (tid == 0) {
        float s1 = red[0][0] + red[1][0] + red[2][0] + red[3][0] + kerb[0];
        float s2 = red[0][1] + red[1][1] + red[2][1] + red[3][1] + gateb[0];
        float s3 = red[0][2] + red[1][2] + red[2][2] + red[3][2] + gateb[1];
        float z = 0.2f * s1;
        float sp = (z > 15.0f) ? z : log1pf(__expf(z));
        float ls = 5.0f * sp;
        ptable[ty * 4 + 0] = 1.0f / (ls * ls);
        ptable[ty * 4 + 1] = 1.0f / (1.0f + __expf(-s2));
        float s = 1.0f / (1.0f + __expf(-s3));
        ptable[ty * 4 + 2] = 1.0f / s;
      }
      __syncthreads();
    }
  }
}

__global__ __launch_bounds__(128) void kf_attn(
    const ushort_t* __restrict__ enc_bf, const float* __restrict__ etime,
    const int* __restrict__ etype, const float* __restrict__ ptable,
    const float* __restrict__ gamma, const float* __restrict__ beta,
    ushort_t* __restrict__ hidden_bf)
{
  __shared__ __align__(16) ushort_t stage[2][2][4096];
  const int tid = threadIdx.x;
  const int lane = tid & 63, wv = tid >> 6;
  const int bk = blockIdx.x;
  const int b = bk & 7;
  const int tl = 127 - (bk >> 3);
  const int base = b * LD;
  const int m = lane & 15, kg = lane >> 4;
  const int i = tl * 16 + m;
  const float ti = etime[base + i];
  const int ty = etype[base + i];
  const float il = ptable[ty * 4 + 0];
  const float ll = ptable[ty * 4 + 1];
  const float is2 = 2.0f * ptable[ty * 4 + 2];
  floatx4 acc[16];
  #pragma unroll
  for (int nt = 0; nt < 16; ++nt) acc[nt] = (floatx4){0.f, 0.f, 0.f, 0.f};
  const int nch = tl / 2 + 1;
  const int myn = (nch > wv) ? ((nch - wv + 1) >> 1) : 0;
  const ushort_t* __restrict__ encC = enc_bf + (size_t)(b * 64) * 8192;
  const int boff = m * 32 + kg * 8;
  ushort_t* buf0 = &stage[wv][0][0];
  ushort_t* buf1 = &stage[wv][1][0];
  if (myn > 0) {
    short8 af;
    int ch = wv;
    {
      float4 ta = *(const float4*)(etime + base + ch * 32 + kg * 8);
      float4 tc = *(const float4*)(etime + base + ch * 32 + kg * 8 + 4);
      const ushort_t* g = encC + (size_t)ch * 8192 + lane * 8;
      #pragma unroll
      for (int q = 0; q < 8; ++q) dma16(g + q * 512, buf0 + q * 512);
      float tj[8] = {ta.x, ta.y, ta.z, ta.w, tc.x, tc.y, tc.z, tc.w};
      af = make_af(ti, i, ch * 32 + kg * 8, tj, il, ll, is2);
      const ushort_t* g2 = g + 8 * 512;
      #pragma unroll
      for (int q = 0; q < 8; ++q) dma16(g2 + q * 512, buf1 + q * 512);
    }
    #pragma unroll 1
    for (int it = 0; it < myn; ++it) {
      const bool more = (it + 1 < myn);
      const int chn = more ? ch + 2 : wv;
      float4 na = *(const float4*)(etime + base + chn * 32 + kg * 8);
      float4 nc = *(const float4*)(etime + base + chn * 32 + kg * 8 + 4);
      __builtin_amdgcn_s_waitcnt(WAIT_VM10);
      #pragma unroll
      for (int q = 0; q < 8; ++q) {
        short8 bf = *(const short8*)(buf0 + q * 512 + boff);
        acc[q] = __builtin_amdgcn_mfma_f32_16x16x32_bf16(af, bf, acc[q], 0, 0, 0);
      }
      {
        const ushort_t* g = encC + (size_t)chn * 8192 + lane * 8;
        #pragma unroll
        for (int q = 0; q < 8; ++q) dma16(g + q * 512, buf0 + q * 512);
      }
      __builtin_amdgcn_s_waitcnt(WAIT_VM10);
      #pragma unroll
      for (int q = 0; q < 8; ++q) {
        short8 bf = *(const short8*)(buf1 + q * 512 + boff);
        acc[8 + q] = __builtin_amdgcn_mfma_f32_16x16x32_bf16(af, bf, acc[8 + q], 0, 0, 0);
      }
      {
        const ushort_t* g = encC + (size_t)chn * 8192 + (8 + 0) * 512 + lane * 8;
        #pragma unroll
        for (int q = 0; q < 8; ++q) dma16(g + q * 512, buf1 + q * 512);
      }
      if (more) {
        float tj[8] = {na.x, na.y, na.z, na.w, nc.x, nc.y, nc.z, nc.w};
        af = make_af(ti, i, chn * 32 + kg * 8, tj, il, ll, is2);
      }
      ch = chn;
    }
  }
  __syncthreads();
  floatx4* reg = (floatx4*)&stage[0][0][0];
  if (wv == 1) {
    #pragma unroll
    for (int nt = 0; nt < 16; ++nt) reg[nt * 64 + lane] = acc[nt];
  }
  __syncthreads();
  if (wv == 0) {
    #pragma unroll
    for (int nt = 0; nt < 16; ++nt) acc[nt] += reg[nt * 64 + lane];
    float gl[16], cl[16];
    #pragma unroll
    for (int nt = 0; nt < 16; ++nt) { gl[nt] = gamma[nt * 16 + m]; cl[nt] = beta[nt * 16 + m]; }
    const int q = lane >> 4;
    #pragma unroll
    for (int r = 0; r < 4; ++r) {
      float h[16];
      float sm = 0.0f, sq = 0.0f;
      #pragma unroll
      for (int nt = 0; nt < 16; ++nt) {
        h[nt] = acc[nt][r];
        sm += h[nt]; sq += h[nt] * h[nt];
      }
      #pragma unroll
      for (int off = 1; off < 16; off <<= 1) {
        sm += __shfl_xor(sm, off);
        sq += __shfl_xor(sq, off);
      }
      float mean = sm * (1.0f / 256.0f);
      float var = sq * (1.0f / 256.0f) - mean * mean;
      float rstd = rsqrtf(var + 1e-6f);
      const int row = q * 4 + r;
      ushort_t* dst = hidden_bf + ((size_t)(base + tl * 16 + row)) * DD + m;
      #pragma unroll
      for (int nt = 0; nt < 16; ++nt)
        dst[nt * 16] = f2bfu((h[nt] - mean) * rstd * gl[nt] + cl[nt]);
    }
  }
}

__global__ __launch_bounds__(256) void kf_gen(
    const ushort_t* __restrict__ noise_bf, const ushort_t* __restrict__ hidden_bf,
    const ushort_t* __restrict__ wcat, const float* __restrict__ wout,
    const float* __restrict__ bout, float* __restrict__ out)
{
  __shared__ float pbuf[4][2][16];
  const int tid = threadIdx.x;
  const int lane = tid & 63, wv = tid >> 6;
  const int m = lane & 15, kg = lane >> 4;
  const int r0 = blockIdx.x * 32 + m;
  const ushort_t* __restrict__ an0 = noise_bf + (size_t)r0 * DD;
  const ushort_t* __restrict__ an1 = noise_bf + (size_t)(r0 + 16) * DD;
  const ushort_t* __restrict__ ah0 = hidden_bf + (size_t)r0 * DD;
  const ushort_t* __restrict__ ah1 = hidden_bf + (size_t)(r0 + 16) * DD;
  floatx4 acc[2][4];
  #pragma unroll
  for (int t = 0; t < 2; ++t)
    #pragma unroll
    for (int n = 0; n < 4; ++n) acc[t][n] = (floatx4){0.f, 0.f, 0.f, 0.f};
  const int slot = m * 32 + kg * 8;
  #pragma unroll
  for (int ks = 0; ks < 16; ++ks) {
    const int koff = (ks & 7) * 32 + kg * 8;
    short8 a0 = *(const short8*)(((ks < 8) ? an0 : ah0) + koff);
    short8 a1 = *(const short8*)(((ks < 8) ? an1 : ah1) + koff);
    #pragma unroll
    for (int n = 0; n < 4; ++n) {
      const ushort_t* bp = wcat + ((size_t)(wv * 4 + n) * 16 + ks) * 512 + slot;
      short8 bf = *(const short8*)bp;
      acc[0][n] = __builtin_amdgcn_mfma_f32_16x16x32_bf16(a0, bf, acc[0][n], 0, 0, 0);
      acc[1][n] = __builtin_amdgcn_mfma_f32_16x16x32_bf16(a1, bf, acc[1][n], 0, 0, 0);
    }
  }
  float wo_l[4];
  #pragma unroll
  for (int n = 0; n < 4; ++n) wo_l[n] = wout[(wv * 4 + n) * 16 + m];
  #pragma unroll
  for (int t = 0; t < 2; ++t) {
    #pragma unroll
    for (int r4 = 0; r4 < 4; ++r4) {
      float p = 0.0f;
      #pragma unroll
      for (int n = 0; n < 4; ++n) p += fmaxf(acc[t][n][r4], 0.0f) * wo_l[n];
      #pragma unroll
      for (int off = 1; off < 16; off <<= 1) p += __shfl_xor(p, off);
      if (m == 0) pbuf[wv][t][kg * 4 + r4] = p;
    }
  }
  __syncthreads();
  if (tid < 32) {
    int t = tid >> 4, rr = tid & 15;
    float x = pbuf[0][t][rr] + pbuf[1][t][rr] + pbuf[2][t][rr] + pbuf[3][t][rr] + bout[0];
    float sp = (x > 15.0f) ? x : log1pf(__expf(x));
    out[blockIdx.x * 32 + t * 16 + rr] = sp;
  }
}

extern "C" void kernel_launch(void* const* d_in, const int* in_sizes, int n_in,
                              void* d_out, int out_size, void* d_ws, size_t ws_size,
                              hipStream_t stream) {
  const int*   etype = (const int*)d_in[0];
  const float* etime = (const float*)d_in[1];
  const float* embw  = (const float*)d_in[2];
  const float* gatew = (const float*)d_in[3];
  const float* gateb = (const float*)d_in[4];
  const float* kerw  = (const float*)d_in[5];
  const float* kerb  = (const float*)d_in[6];
  const float* gamma = (const float*)d_in[7];
  const float* beta  = (const float*)d_in[8];
  const float* wi    = (const float*)d_in[9];   // gen_input_w
  const float* wn    = (const float*)d_in[10];  // gen_noise_w
  const float* wo    = (const float*)d_in[11];  // gen_out_w
  const float* bo    = (const float*)d_in[12];  // gen_out_b
  const float* noise = (const float*)d_in[13];
  float* out = (float*)d_out;

  char* w8 = (char*)d_ws;
  float* ptable       = (float*)(w8);
  ushort_t* enc_bf    = (ushort_t*)(w8 + 262144);
  ushort_t* hidden_bf = (ushort_t*)(w8 + 262144 + 8388608);
  ushort_t* noise_bf  = (ushort_t*)(w8 + 262144 + 2 * 8388608);
  ushort_t* wcat      = (ushort_t*)(w8 + 262144 + 3 * 8388608);

  int occ = 0;
  hipError_t e = hipOccupancyMaxActiveBlocksPerMultiprocessor(&occ, k_fused, 128, 0);
  bool coop = (e == hipSuccess && occ >= 2);
  if (coop) {
    void* args[] = {
        (void*)&etype, (void*)&etime, (void*)&embw, (void*)&gatew, (void*)&gateb,
        (void*)&kerw, (void*)&kerb, (void*)&gamma, (void*)&beta, (void*)&wi,
        (void*)&wn, (void*)&wo, (void*)&bo, (void*)&noise, (void*)&out,
        (void*)&enc_bf, (void*)&noise_bf, (void*)&wcat, (void*)&ptable,
        (void*)&hidden_bf};
    e = hipLaunchCooperativeKernel((const void*)k_fused, dim3(512), dim3(128),
                                   args, 0, stream);
    coop = (e == hipSuccess);
  }
  if (!coop) {   // known-good r9 path
    kf_prep<<<4737, 256, 0, stream>>>(etype, etime, embw, gatew, gateb, kerw, kerb,
                                      noise, wn, wi, enc_bf, noise_bf, wcat, ptable);
    kf_attn<<<1024, 128, 0, stream>>>(enc_bf, etime, etype, ptable,
                                      gamma, beta, hidden_bf);
    kf_gen<<<512, 256, 0, stream>>>(noise_bf, hidden_bf, wcat, wo, bo, out);
  }
}